// Round 10
// baseline (1969.214 us; speedup 1.0000x reference)
//
#include <hip/hip_runtime.h>
#include <hip/hip_bf16.h>

#define N_NODES 100000
#define N_PAD 100032          // 1563 * 64
#define MM_BLOCKS 1563        // N_PAD / 64
#define N_EDGES 3200000
#define N_GRAPHS 1024
#define DIM 128
#define BN_EPS 1e-5f
#define SCAN_CHUNK 391        // 256 * 391 = 100096 >= N_NODES

typedef __attribute__((ext_vector_type(8))) short short8;
typedef __attribute__((ext_vector_type(4))) float floatx4;

__device__ __forceinline__ float bits2f(unsigned short u) {
    return __uint_as_float(((unsigned int)u) << 16);
}
__device__ __forceinline__ unsigned short f2b_rne(float f) {
    unsigned int u = __float_as_uint(f);
    unsigned int r = u + 0x7FFFu + ((u >> 16) & 1u);
    return (unsigned short)(r >> 16);
}
__device__ __forceinline__ float lo2f(unsigned int u) { return __uint_as_float(u << 16); }
__device__ __forceinline__ float hi2f(unsigned int u) { return __uint_as_float(u & 0xFFFF0000u); }

// ---------------- x (fp32) -> bf16 Hb0, vectorized ----------------
__global__ __launch_bounds__(256) void k_cvt0(const float4* __restrict__ x4,
                                              ushort4* __restrict__ o4) {
    size_t i = (size_t)blockIdx.x * 256 + threadIdx.x;   // exactly 3,200,000
    float4 v = x4[i];
    ushort4 o;
    o.x = f2b_rne(v.x); o.y = f2b_rne(v.y); o.z = f2b_rne(v.z); o.w = f2b_rne(v.w);
    o4[i] = o;
}

// ---------------- graph boundaries (batch sorted) ----------------

__global__ __launch_bounds__(256) void k_binit(int* __restrict__ startv, int* __restrict__ endv) {
    int i = blockIdx.x * 256 + threadIdx.x;
    if (i < N_GRAPHS) { startv[i] = 0; endv[i] = 0; }
}

__global__ __launch_bounds__(256) void k_bounds(const int* __restrict__ batch,
                                                int* __restrict__ startv, int* __restrict__ endv) {
    int i = blockIdx.x * 256 + threadIdx.x;
    if (i >= N_NODES) return;
    int g = batch[i];
    if (i == 0 || batch[i - 1] != g) startv[g] = i;
    if (i == N_NODES - 1 || batch[i + 1] != g) endv[g] = i + 1;
}

// ---------------- CSR build ----------------

__global__ __launch_bounds__(256) void k_izero(int* __restrict__ p, int n) {
    int i = blockIdx.x * 256 + threadIdx.x;
    if (i < n) p[i] = 0;
}

// degree count; the atomic's return value IS this edge's rank within its dst
__global__ __launch_bounds__(256) void k_deg(const int* __restrict__ ei,
                                             int* __restrict__ deg,
                                             int* __restrict__ rank) {
    int e = blockIdx.x * 256 + threadIdx.x;
    if (e < N_EDGES) rank[e] = atomicAdd(&deg[ei[N_EDGES + e]], 1);
}

// hierarchical scan: A) per-block sums  B) scan of 256 block sums  C) per-node offsets
__global__ __launch_bounds__(256) void k_scanA(const int* __restrict__ deg, int* __restrict__ bsum) {
    __shared__ int red[256];
    int b = blockIdx.x, t = threadIdx.x;
    int base = b * SCAN_CHUNK;
    int end = base + SCAN_CHUNK; if (end > N_NODES) end = N_NODES;
    int s = 0;
    for (int i = base + t; i < end; i += 256) s += deg[i];
    red[t] = s; __syncthreads();
    for (int st = 128; st > 0; st >>= 1) { if (t < st) red[t] += red[t + st]; __syncthreads(); }
    if (t == 0) bsum[b] = red[0];
}

__global__ __launch_bounds__(256) void k_scanB(const int* __restrict__ bsum,
                                               int* __restrict__ bbase, int* __restrict__ offend) {
    __shared__ int v[256];
    int t = threadIdx.x;
    int mine = bsum[t];
    v[t] = mine; __syncthreads();
    for (int d = 1; d < 256; d <<= 1) {
        int x = (t >= d) ? v[t - d] : 0; __syncthreads();
        v[t] += x; __syncthreads();
    }
    bbase[t] = v[t] - mine;
    if (t == 255) *offend = v[255];
}

__global__ __launch_bounds__(256) void k_scanC(const int* __restrict__ deg,
                                               const int* __restrict__ bbase,
                                               int* __restrict__ off) {
    __shared__ int red[256];
    int b = blockIdx.x, t = threadIdx.x;
    int base = b * SCAN_CHUNK;
    int end = base + SCAN_CHUNK; if (end > N_NODES) end = N_NODES;
    int n0 = base + 2 * t, n1 = n0 + 1;
    int d0 = (n0 < end) ? deg[n0] : 0;
    int d1 = (n1 < end) ? deg[n1] : 0;
    int mine = d0 + d1;
    red[t] = mine; __syncthreads();
    for (int d = 1; d < 256; d <<= 1) {
        int x = (t >= d) ? red[t - d] : 0; __syncthreads();
        red[t] += x; __syncthreads();
    }
    int excl = red[t] - mine + bbase[b];
    if (n0 < end) off[n0] = excl;
    if (n1 < end) off[n1] = excl + d0;
}

// atomic-free fill: position = off[dst] + rank (captured in k_deg)
__global__ __launch_bounds__(256) void k_fill(const int* __restrict__ ei,
                                              const int* __restrict__ off,
                                              const int* __restrict__ rank,
                                              int* __restrict__ csr_src) {
    int e = blockIdx.x * 256 + threadIdx.x;
    if (e < N_EDGES) {
        int dst = ei[N_EDGES + e];
        csr_src[off[dst] + rank[e]] = ei[e];
    }
}

// ------- weight transpose + fp32->bf16: Wt[mat][n*128+k] = bf16(W[mat][k*128+n])
__global__ __launch_bounds__(256) void k_tw(const float* __restrict__ w1,
                                            const float* __restrict__ w2,
                                            const float* __restrict__ lw1,
                                            const float* __restrict__ lw2,
                                            unsigned short* __restrict__ Wt) {
    int bid = blockIdx.x;                     // 512 blocks
    int mat = bid >> 6;
    int t = (bid & 63) * 256 + threadIdx.x;   // 0..16383
    int k = t >> 7, n = t & 127;
    const float* src;
    if (mat == 0) src = w1;
    else if (mat == 1) src = w2;
    else if (mat < 5) src = lw1 + (size_t)(mat - 2) * 16384;
    else src = lw2 + (size_t)(mat - 5) * 16384;
    Wt[(size_t)mat * 16384 + n * 128 + k] = f2b_rne(src[t]);
}

// ---------------- aggregation: A[dst] = H[dst] + sum_{src in N(dst)} H[src] --
__global__ __launch_bounds__(256) void k_agg(const uint4* __restrict__ H4,
                                             const int* __restrict__ off,
                                             const int* __restrict__ csr_src,
                                             uint4* __restrict__ A4) {
    int wave = threadIdx.x >> 6;
    int lane = threadIdx.x & 63;
    int g4 = lane >> 4;        // neighbor sub-slot 0..3
    int c = lane & 15;         // uint4 index within 256B row
    int dst = blockIdx.x * 4 + wave;
    if (dst >= N_NODES) return;
    int s = off[dst], e = off[dst + 1];

    float acc[8];
    {
        uint4 h = H4[(size_t)dst * 16 + c];
        if (g4 == 0) {
            acc[0] = lo2f(h.x); acc[1] = hi2f(h.x);
            acc[2] = lo2f(h.y); acc[3] = hi2f(h.y);
            acc[4] = lo2f(h.z); acc[5] = hi2f(h.z);
            acc[6] = lo2f(h.w); acc[7] = hi2f(h.w);
        } else {
#pragma unroll
            for (int j = 0; j < 8; ++j) acc[j] = 0.f;
        }
    }

#define ADD8(v) do { \
        acc[0] += lo2f((v).x); acc[1] += hi2f((v).x); \
        acc[2] += lo2f((v).y); acc[3] += hi2f((v).y); \
        acc[4] += lo2f((v).z); acc[5] += hi2f((v).z); \
        acc[6] += lo2f((v).w); acc[7] += hi2f((v).w); } while (0)

    int i = s;
    for (; i + 32 <= e; i += 32) {
        int i0 = i + g4;
        int s0 = csr_src[i0];
        int s1 = csr_src[i0 + 4];
        int s2 = csr_src[i0 + 8];
        int s3 = csr_src[i0 + 12];
        int s4 = csr_src[i0 + 16];
        int s5 = csr_src[i0 + 20];
        int s6 = csr_src[i0 + 24];
        int s7 = csr_src[i0 + 28];
        uint4 v0 = H4[(size_t)s0 * 16 + c];
        uint4 v1 = H4[(size_t)s1 * 16 + c];
        uint4 v2 = H4[(size_t)s2 * 16 + c];
        uint4 v3 = H4[(size_t)s3 * 16 + c];
        uint4 v4 = H4[(size_t)s4 * 16 + c];
        uint4 v5 = H4[(size_t)s5 * 16 + c];
        uint4 v6 = H4[(size_t)s6 * 16 + c];
        uint4 v7 = H4[(size_t)s7 * 16 + c];
        ADD8(v0); ADD8(v1); ADD8(v2); ADD8(v3);
        ADD8(v4); ADD8(v5); ADD8(v6); ADD8(v7);
    }
    if (i + 16 <= e) {
        int i0 = i + g4;
        int s0 = csr_src[i0];
        int s1 = csr_src[i0 + 4];
        int s2 = csr_src[i0 + 8];
        int s3 = csr_src[i0 + 12];
        uint4 v0 = H4[(size_t)s0 * 16 + c];
        uint4 v1 = H4[(size_t)s1 * 16 + c];
        uint4 v2 = H4[(size_t)s2 * 16 + c];
        uint4 v3 = H4[(size_t)s3 * 16 + c];
        ADD8(v0); ADD8(v1); ADD8(v2); ADD8(v3);
        i += 16;
    }
    for (; i < e; i += 4) {
        int idx = i + g4;
        bool valid = idx < e;
        int src = csr_src[valid ? idx : (e - 1)];
        uint4 v = H4[(size_t)src * 16 + c];
        if (valid) ADD8(v);
    }
#undef ADD8

#pragma unroll
    for (int j = 0; j < 8; ++j) {
        acc[j] += __shfl_xor(acc[j], 16, 64);
        acc[j] += __shfl_xor(acc[j], 32, 64);
    }
    if (g4 == 0) {
        uint4 o;
        o.x = (unsigned int)f2b_rne(acc[0]) | ((unsigned int)f2b_rne(acc[1]) << 16);
        o.y = (unsigned int)f2b_rne(acc[2]) | ((unsigned int)f2b_rne(acc[3]) << 16);
        o.z = (unsigned int)f2b_rne(acc[4]) | ((unsigned int)f2b_rne(acc[5]) << 16);
        o.w = (unsigned int)f2b_rne(acc[6]) | ((unsigned int)f2b_rne(acc[7]) << 16);
        A4[(size_t)dst * 16 + c] = o;
    }
}

// ------- MFMA GEMM 1: Yb = bf16(A @ W1 + b1), fused BN column stats ---------
// Stats computed in fp32 from the UNROUNDED accumulators; per-block partials.
__global__ __launch_bounds__(256) void k_mm1(const unsigned short* __restrict__ A,
                                             const unsigned short* __restrict__ Wt,
                                             const float* __restrict__ bias,
                                             unsigned short* __restrict__ Yb,
                                             float* __restrict__ partials) {
    __shared__ float sWS[4 * 128];
    __shared__ float s2WS[4 * 128];
    int wave = threadIdx.x >> 6, lane = threadIdx.x & 63;
    int quad = lane >> 4, l16 = lane & 15;
    int mload = blockIdx.x * 64 + wave * 16 + l16;      // < N_PAD

    short8 a[4];
    const unsigned short* arow = A + (size_t)mload * 128 + quad * 8;
#pragma unroll
    for (int kc = 0; kc < 4; ++kc) a[kc] = *(const short8*)(arow + kc * 32);

    floatx4 acc[8];
#pragma unroll
    for (int nt = 0; nt < 8; ++nt) {
        floatx4 z = {0.f, 0.f, 0.f, 0.f};
        acc[nt] = z;
        const unsigned short* wrow = Wt + (size_t)(nt * 16 + l16) * 128 + quad * 8;
#pragma unroll
        for (int kc = 0; kc < 4; ++kc) {
            short8 b = *(const short8*)(wrow + kc * 32);
            acc[nt] = __builtin_amdgcn_mfma_f32_16x16x32_bf16(a[kc], b, acc[nt], 0, 0, 0);
        }
    }

    int mrow0 = blockIdx.x * 64 + wave * 16 + quad * 4;
    float s_nt[8], s2_nt[8];
#pragma unroll
    for (int nt = 0; nt < 8; ++nt) {
        int n = nt * 16 + l16;
        float bn = bias[n];
        float s = 0.f, s2 = 0.f;
#pragma unroll
        for (int r = 0; r < 4; ++r) {
            int mm = mrow0 + r;
            if (mm < N_NODES) {
                float val = acc[nt][r] + bn;
                Yb[(size_t)mm * 128 + n] = f2b_rne(val);
                s += val;
                s2 = fmaf(val, val, s2);
            }
        }
        s_nt[nt] = s; s2_nt[nt] = s2;
    }
    // reduce over quads (lanes l16, +16, +32, +48)
#pragma unroll
    for (int nt = 0; nt < 8; ++nt) {
        s_nt[nt] += __shfl_xor(s_nt[nt], 16, 64);
        s_nt[nt] += __shfl_xor(s_nt[nt], 32, 64);
        s2_nt[nt] += __shfl_xor(s2_nt[nt], 16, 64);
        s2_nt[nt] += __shfl_xor(s2_nt[nt], 32, 64);
    }
    if (quad == 0) {
#pragma unroll
        for (int nt = 0; nt < 8; ++nt) {
            sWS[wave * 128 + nt * 16 + l16] = s_nt[nt];
            s2WS[wave * 128 + nt * 16 + l16] = s2_nt[nt];
        }
    }
    __syncthreads();
    int tid = threadIdx.x;
    if (tid < 128) {
        float v = sWS[tid] + sWS[128 + tid] + sWS[256 + tid] + sWS[384 + tid];
        partials[(size_t)blockIdx.x * 256 + tid] = v;
    } else {
        int cc = tid - 128;
        float v = s2WS[cc] + s2WS[128 + cc] + s2WS[256 + cc] + s2WS[384 + cc];
        partials[(size_t)blockIdx.x * 256 + 128 + cc] = v;
    }
}

__global__ __launch_bounds__(256) void k_finalize(const float* __restrict__ partials,
                                                  float* __restrict__ stats,
                                                  const float* __restrict__ g,
                                                  const float* __restrict__ be) {
    __shared__ float red[256];
    int tid = threadIdx.x;
    float s = 0.f;
#pragma unroll 4
    for (int b = 0; b < MM_BLOCKS; ++b) s += partials[(size_t)b * 256 + tid];
    red[tid] = s;
    __syncthreads();
    if (tid < 128) {
        float sum = red[tid], sumsq = red[128 + tid];
        const float invN = 1.f / (float)N_NODES;
        float m = sum * invN;
        float v = sumsq * invN - m * m;
        float rstd = rsqrtf(v + BN_EPS);
        float sca = g[tid] * rstd;
        stats[tid] = sca;
        stats[128 + tid] = be[tid] - m * sca;
    }
}

// ---- MFMA GEMM 2: H = relu( relu(Yb*sc+sh) @ W2 + b2 ), bf16 in/out --------
__global__ __launch_bounds__(256) void k_mm2(const unsigned short* __restrict__ Yb,
                                             const unsigned short* __restrict__ Wt,
                                             const float* __restrict__ bias,
                                             const float* __restrict__ stats,
                                             unsigned short* __restrict__ Hb) {
    int wave = threadIdx.x >> 6, lane = threadIdx.x & 63;
    int quad = lane >> 4, l16 = lane & 15;
    int mload = blockIdx.x * 64 + wave * 16 + l16;

    const unsigned short* yrow = Yb + (size_t)mload * 128;
    short8 a[4];
#pragma unroll
    for (int kc = 0; kc < 4; ++kc) {
        int k0 = kc * 32 + quad * 8;
        union { short8 s8; unsigned short u[8]; } q, p;
        q.s8 = *(const short8*)(yrow + k0);
#pragma unroll
        for (int j = 0; j < 8; ++j) {
            float sc = stats[k0 + j];
            float sh = stats[128 + k0 + j];
            float t = fmaxf(fmaf(bits2f(q.u[j]), sc, sh), 0.f);
            p.u[j] = f2b_rne(t);
        }
        a[kc] = p.s8;
    }

    floatx4 acc[8];
#pragma unroll
    for (int nt = 0; nt < 8; ++nt) {
        floatx4 z = {0.f, 0.f, 0.f, 0.f};
        acc[nt] = z;
        const unsigned short* wrow = Wt + (size_t)(nt * 16 + l16) * 128 + quad * 8;
#pragma unroll
        for (int kc = 0; kc < 4; ++kc) {
            short8 b = *(const short8*)(wrow + kc * 32);
            acc[nt] = __builtin_amdgcn_mfma_f32_16x16x32_bf16(a[kc], b, acc[nt], 0, 0, 0);
        }
    }

    int mrow0 = blockIdx.x * 64 + wave * 16 + quad * 4;
#pragma unroll
    for (int nt = 0; nt < 8; ++nt) {
        int n = nt * 16 + l16;
        float bn = bias[n];
#pragma unroll
        for (int r = 0; r < 4; ++r) {
            int mm = mrow0 + r;
            if (mm < N_NODES) {
                float h = fmaxf(acc[nt][r] + bn, 0.f);
                Hb[(size_t)mm * 128 + n] = f2b_rne(h);
            }
        }
    }
}

// ---------------- global add pool (bf16 in, fp32 out), row-unrolled ---------

__global__ __launch_bounds__(128) void k_pool(const unsigned short* __restrict__ Hb,
                                              const int* __restrict__ startv,
                                              const int* __restrict__ endv,
                                              float* __restrict__ gr, int loff) {
    int g = blockIdx.x;
    int c = threadIdx.x;
    int s = startv[g], e = endv[g];
    float acc = 0.f;
    int r = s;
    for (; r + 4 <= e; r += 4) {
        unsigned short a0 = Hb[(size_t)r * 128 + c];
        unsigned short a1 = Hb[(size_t)(r + 1) * 128 + c];
        unsigned short a2 = Hb[(size_t)(r + 2) * 128 + c];
        unsigned short a3 = Hb[(size_t)(r + 3) * 128 + c];
        acc += bits2f(a0) + bits2f(a1) + bits2f(a2) + bits2f(a3);
    }
    for (; r < e; ++r) acc += bits2f(Hb[(size_t)r * 128 + c]);
    gr[(size_t)g * (4 * DIM) + loff + c] = acc;
}

// ---------------- classifier (fp32 weights, fp32 out) ----------------

__global__ __launch_bounds__(128) void k_cls1(const float* __restrict__ gr,
                                              const float* __restrict__ w,
                                              const float* __restrict__ b,
                                              float* __restrict__ out) {
    __shared__ float row[512];
    int g = blockIdx.x, tid = threadIdx.x;
    for (int i = tid; i < 512; i += 128) row[i] = gr[(size_t)g * 512 + i];
    __syncthreads();
    float acc = b[tid];
    for (int k = 0; k < 512; ++k) acc = fmaf(row[k], w[k * 128 + tid], acc);
    out[(size_t)g * 128 + tid] = fmaxf(acc, 0.f);
}

__global__ __launch_bounds__(64) void k_cls2(const float* __restrict__ gr1,
                                             const float* __restrict__ w,
                                             const float* __restrict__ b,
                                             float* __restrict__ out) {
    __shared__ float row[128];
    int g = blockIdx.x, tid = threadIdx.x;
    row[tid] = gr1[(size_t)g * 128 + tid];
    row[tid + 64] = gr1[(size_t)g * 128 + tid + 64];
    __syncthreads();
    float acc = b[tid];
    for (int k = 0; k < 128; ++k) acc = fmaf(row[k], w[k * 64 + tid], acc);
    out[(size_t)g * 64 + tid] = fmaxf(acc, 0.f);
}

__global__ __launch_bounds__(256) void k_cls3(const float* __restrict__ gr2,
                                              const float* __restrict__ w,
                                              const float* __restrict__ b,
                                              float* __restrict__ out) {
    int idx = blockIdx.x * 256 + threadIdx.x;
    if (idx < N_GRAPHS * 2) {
        int g = idx >> 1, j = idx & 1;
        float acc = b[j];
        const float* r = gr2 + (size_t)g * 64;
        for (int k = 0; k < 64; ++k) acc = fmaf(r[k], w[k * 2 + j], acc);
        out[idx] = acc;
    }
}

// ---------------- launch ----------------

extern "C" void kernel_launch(void* const* d_in, const int* in_sizes, int n_in,
                              void* d_out, int out_size, void* d_ws, size_t ws_size,
                              hipStream_t stream) {
    const float* x = (const float*)d_in[0];
    const int* ei = (const int*)d_in[1];
    const int* batch = (const int*)d_in[2];
    const float* b1 = (const float*)d_in[4];
    const float* g1 = (const float*)d_in[5];
    const float* be1 = (const float*)d_in[6];
    const float* b2 = (const float*)d_in[8];
    const float* lb1 = (const float*)d_in[10];
    const float* lg1 = (const float*)d_in[11];
    const float* lbe1 = (const float*)d_in[12];
    const float* lb2 = (const float*)d_in[14];
    const float* cw1 = (const float*)d_in[15];
    const float* cb1 = (const float*)d_in[16];
    const float* cw2 = (const float*)d_in[17];
    const float* cb2 = (const float*)d_in[18];
    const float* cw3 = (const float*)d_in[19];
    const float* cb3 = (const float*)d_in[20];

    // workspace layout (float units; every segment 16B-aligned)
    float* ws = (float*)d_ws;
    unsigned short* Yb = (unsigned short*)ws;                     // N_PAD*128 bf16
    float* gr = ws + (size_t)N_PAD * 64;                          // 1024*512
    float* gr1 = gr + (size_t)N_GRAPHS * 512;                     // 1024*128
    float* gr2 = gr1 + (size_t)N_GRAPHS * 128;                    // 1024*64
    float* stats = gr2 + (size_t)N_GRAPHS * 64;                   // 256
    float* partials = stats + 256;                                // 1563*256
    float* p_end = partials + (size_t)MM_BLOCKS * 256;
    int* startv = (int*)p_end;
    int* endv = startv + N_GRAPHS;
    unsigned short* Wt = (unsigned short*)(endv + N_GRAPHS);      // 8*16384 bf16
    unsigned short* A = Wt + (size_t)8 * 16384;                   // N_PAD*128 bf16
    unsigned short* Hb0 = A + (size_t)N_PAD * 128;                // bf16(x)
    unsigned short* Hb1 = Hb0 + (size_t)N_NODES * 128;            // layer H
    int* deg = (int*)(Hb1 + (size_t)N_NODES * 128);               // N_NODES
    int* rank = deg + N_NODES;                                    // N_EDGES
    int* offarr = rank + N_EDGES;                                 // N_NODES+1
    int* csr_src = offarr + (N_NODES + 4);                        // N_EDGES (padded align)
    int* bsum = csr_src + N_EDGES;                                // 256
    int* bbase = bsum + 256;                                      // 256

    k_cvt0<<<12500, 256, 0, stream>>>((const float4*)x, (ushort4*)Hb0);
    k_binit<<<4, 256, 0, stream>>>(startv, endv);
    k_bounds<<<(N_NODES + 255) / 256, 256, 0, stream>>>(batch, startv, endv);
    k_izero<<<(N_NODES + 255) / 256, 256, 0, stream>>>(deg, N_NODES);
    k_deg<<<N_EDGES / 256, 256, 0, stream>>>(ei, deg, rank);
    k_scanA<<<256, 256, 0, stream>>>(deg, bsum);
    k_scanB<<<1, 256, 0, stream>>>(bsum, bbase, &offarr[N_NODES]);
    k_scanC<<<256, 256, 0, stream>>>(deg, bbase, offarr);
    k_fill<<<N_EDGES / 256, 256, 0, stream>>>(ei, offarr, rank, csr_src);
    k_tw<<<512, 256, 0, stream>>>((const float*)d_in[3], (const float*)d_in[7],
                                  (const float*)d_in[9], (const float*)d_in[13], Wt);

    for (int l = 0; l < 4; ++l) {
        const unsigned short* aggIn = (l == 0) ? Hb0 : Hb1;

        const unsigned short* W1t = Wt + (size_t)((l == 0) ? 0 : (1 + l)) * 16384;
        const unsigned short* W2t = Wt + (size_t)((l == 0) ? 1 : (4 + l)) * 16384;
        const float* B1 = (l == 0) ? b1 : lb1 + (size_t)(l - 1) * 128;
        const float* B2 = (l == 0) ? b2 : lb2 + (size_t)(l - 1) * 128;
        const float* G = (l == 0) ? g1 : lg1 + (size_t)(l - 1) * 128;
        const float* BE = (l == 0) ? be1 : lbe1 + (size_t)(l - 1) * 128;

        k_agg<<<N_NODES / 4, 256, 0, stream>>>((const uint4*)aggIn, offarr, csr_src,
                                               (uint4*)A);
        k_mm1<<<MM_BLOCKS, 256, 0, stream>>>(A, W1t, B1, Yb, partials);
        k_finalize<<<1, 256, 0, stream>>>(partials, stats, G, BE);
        k_mm2<<<MM_BLOCKS, 256, 0, stream>>>(Yb, W2t, B2, stats, Hb1);
        k_pool<<<N_GRAPHS, 128, 0, stream>>>(Hb1, startv, endv, gr, l * DIM);
    }

    k_cls1<<<N_GRAPHS, 128, 0, stream>>>(gr, cw1, cb1, gr1);
    k_cls2<<<N_GRAPHS, 64, 0, stream>>>(gr1, cw2, cb2, gr2);
    k_cls3<<<8, 256, 0, stream>>>(gr2, cw3, cb3, (float*)d_out);
}

// Round 11
// 1256.151 us; speedup vs baseline: 1.5677x; 1.5677x over previous
//
#include <hip/hip_runtime.h>
#include <hip/hip_bf16.h>

#define N_NODES 100000
#define N_PAD 100032          // 1563 * 64
#define MM_BLOCKS 1563        // N_PAD / 64
#define RED_BLOCKS 64
#define N_EDGES 3200000
#define N_GRAPHS 1024
#define DIM 128
#define BN_EPS 1e-5f
#define SCAN_CHUNK 391        // 256 * 391 = 100096 >= N_NODES

typedef __attribute__((ext_vector_type(8))) short short8;
typedef __attribute__((ext_vector_type(4))) float floatx4;

__device__ __forceinline__ float bits2f(unsigned short u) {
    return __uint_as_float(((unsigned int)u) << 16);
}
__device__ __forceinline__ unsigned short f2b_rne(float f) {
    unsigned int u = __float_as_uint(f);
    unsigned int r = u + 0x7FFFu + ((u >> 16) & 1u);
    return (unsigned short)(r >> 16);
}
__device__ __forceinline__ float lo2f(unsigned int u) { return __uint_as_float(u << 16); }
__device__ __forceinline__ float hi2f(unsigned int u) { return __uint_as_float(u & 0xFFFF0000u); }

// ---------------- x (fp32) -> bf16 Hb0, vectorized ----------------
__global__ __launch_bounds__(256) void k_cvt0(const float4* __restrict__ x4,
                                              ushort4* __restrict__ o4) {
    size_t i = (size_t)blockIdx.x * 256 + threadIdx.x;   // exactly 3,200,000
    float4 v = x4[i];
    ushort4 o;
    o.x = f2b_rne(v.x); o.y = f2b_rne(v.y); o.z = f2b_rne(v.z); o.w = f2b_rne(v.w);
    o4[i] = o;
}

// ---------------- graph boundaries (batch sorted) ----------------

__global__ __launch_bounds__(256) void k_binit(int* __restrict__ startv, int* __restrict__ endv) {
    int i = blockIdx.x * 256 + threadIdx.x;
    if (i < N_GRAPHS) { startv[i] = 0; endv[i] = 0; }
}

__global__ __launch_bounds__(256) void k_bounds(const int* __restrict__ batch,
                                                int* __restrict__ startv, int* __restrict__ endv) {
    int i = blockIdx.x * 256 + threadIdx.x;
    if (i >= N_NODES) return;
    int g = batch[i];
    if (i == 0 || batch[i - 1] != g) startv[g] = i;
    if (i == N_NODES - 1 || batch[i + 1] != g) endv[g] = i + 1;
}

// ---------------- CSR build ----------------

__global__ __launch_bounds__(256) void k_izero(int* __restrict__ p, int n) {
    int i = blockIdx.x * 256 + threadIdx.x;
    if (i < n) p[i] = 0;
}

// degree count; the atomic's return value IS this edge's rank within its dst
__global__ __launch_bounds__(256) void k_deg(const int* __restrict__ ei,
                                             int* __restrict__ deg,
                                             int* __restrict__ rank) {
    int e = blockIdx.x * 256 + threadIdx.x;
    if (e < N_EDGES) rank[e] = atomicAdd(&deg[ei[N_EDGES + e]], 1);
}

// hierarchical scan: A) per-block sums  B) scan of 256 block sums  C) per-node offsets
__global__ __launch_bounds__(256) void k_scanA(const int* __restrict__ deg, int* __restrict__ bsum) {
    __shared__ int red[256];
    int b = blockIdx.x, t = threadIdx.x;
    int base = b * SCAN_CHUNK;
    int end = base + SCAN_CHUNK; if (end > N_NODES) end = N_NODES;
    int s = 0;
    for (int i = base + t; i < end; i += 256) s += deg[i];
    red[t] = s; __syncthreads();
    for (int st = 128; st > 0; st >>= 1) { if (t < st) red[t] += red[t + st]; __syncthreads(); }
    if (t == 0) bsum[b] = red[0];
}

__global__ __launch_bounds__(256) void k_scanB(const int* __restrict__ bsum,
                                               int* __restrict__ bbase, int* __restrict__ offend) {
    __shared__ int v[256];
    int t = threadIdx.x;
    int mine = bsum[t];
    v[t] = mine; __syncthreads();
    for (int d = 1; d < 256; d <<= 1) {
        int x = (t >= d) ? v[t - d] : 0; __syncthreads();
        v[t] += x; __syncthreads();
    }
    bbase[t] = v[t] - mine;
    if (t == 255) *offend = v[255];
}

__global__ __launch_bounds__(256) void k_scanC(const int* __restrict__ deg,
                                               const int* __restrict__ bbase,
                                               int* __restrict__ off) {
    __shared__ int red[256];
    int b = blockIdx.x, t = threadIdx.x;
    int base = b * SCAN_CHUNK;
    int end = base + SCAN_CHUNK; if (end > N_NODES) end = N_NODES;
    int n0 = base + 2 * t, n1 = n0 + 1;
    int d0 = (n0 < end) ? deg[n0] : 0;
    int d1 = (n1 < end) ? deg[n1] : 0;
    int mine = d0 + d1;
    red[t] = mine; __syncthreads();
    for (int d = 1; d < 256; d <<= 1) {
        int x = (t >= d) ? red[t - d] : 0; __syncthreads();
        red[t] += x; __syncthreads();
    }
    int excl = red[t] - mine + bbase[b];
    if (n0 < end) off[n0] = excl;
    if (n1 < end) off[n1] = excl + d0;
}

// atomic-free fill: position = off[dst] + rank (captured in k_deg)
__global__ __launch_bounds__(256) void k_fill(const int* __restrict__ ei,
                                              const int* __restrict__ off,
                                              const int* __restrict__ rank,
                                              int* __restrict__ csr_src) {
    int e = blockIdx.x * 256 + threadIdx.x;
    if (e < N_EDGES) {
        int dst = ei[N_EDGES + e];
        csr_src[off[dst] + rank[e]] = ei[e];
    }
}

// ------- weight transpose + fp32->bf16: Wt[mat][n*128+k] = bf16(W[mat][k*128+n])
__global__ __launch_bounds__(256) void k_tw(const float* __restrict__ w1,
                                            const float* __restrict__ w2,
                                            const float* __restrict__ lw1,
                                            const float* __restrict__ lw2,
                                            unsigned short* __restrict__ Wt) {
    int bid = blockIdx.x;                     // 512 blocks
    int mat = bid >> 6;
    int t = (bid & 63) * 256 + threadIdx.x;   // 0..16383
    int k = t >> 7, n = t & 127;
    const float* src;
    if (mat == 0) src = w1;
    else if (mat == 1) src = w2;
    else if (mat < 5) src = lw1 + (size_t)(mat - 2) * 16384;
    else src = lw2 + (size_t)(mat - 5) * 16384;
    Wt[(size_t)mat * 16384 + n * 128 + k] = f2b_rne(src[t]);
}

// ---------------- aggregation: A[dst] = H[dst] + sum_{src in N(dst)} H[src] --
__global__ __launch_bounds__(256) void k_agg(const uint4* __restrict__ H4,
                                             const int* __restrict__ off,
                                             const int* __restrict__ csr_src,
                                             uint4* __restrict__ A4) {
    int wave = threadIdx.x >> 6;
    int lane = threadIdx.x & 63;
    int g4 = lane >> 4;        // neighbor sub-slot 0..3
    int c = lane & 15;         // uint4 index within 256B row
    int dst = blockIdx.x * 4 + wave;
    if (dst >= N_NODES) return;
    int s = off[dst], e = off[dst + 1];

    float acc[8];
    {
        uint4 h = H4[(size_t)dst * 16 + c];
        if (g4 == 0) {
            acc[0] = lo2f(h.x); acc[1] = hi2f(h.x);
            acc[2] = lo2f(h.y); acc[3] = hi2f(h.y);
            acc[4] = lo2f(h.z); acc[5] = hi2f(h.z);
            acc[6] = lo2f(h.w); acc[7] = hi2f(h.w);
        } else {
#pragma unroll
            for (int j = 0; j < 8; ++j) acc[j] = 0.f;
        }
    }

#define ADD8(v) do { \
        acc[0] += lo2f((v).x); acc[1] += hi2f((v).x); \
        acc[2] += lo2f((v).y); acc[3] += hi2f((v).y); \
        acc[4] += lo2f((v).z); acc[5] += hi2f((v).z); \
        acc[6] += lo2f((v).w); acc[7] += hi2f((v).w); } while (0)

    int i = s;
    for (; i + 32 <= e; i += 32) {
        int i0 = i + g4;
        int s0 = csr_src[i0];
        int s1 = csr_src[i0 + 4];
        int s2 = csr_src[i0 + 8];
        int s3 = csr_src[i0 + 12];
        int s4 = csr_src[i0 + 16];
        int s5 = csr_src[i0 + 20];
        int s6 = csr_src[i0 + 24];
        int s7 = csr_src[i0 + 28];
        uint4 v0 = H4[(size_t)s0 * 16 + c];
        uint4 v1 = H4[(size_t)s1 * 16 + c];
        uint4 v2 = H4[(size_t)s2 * 16 + c];
        uint4 v3 = H4[(size_t)s3 * 16 + c];
        uint4 v4 = H4[(size_t)s4 * 16 + c];
        uint4 v5 = H4[(size_t)s5 * 16 + c];
        uint4 v6 = H4[(size_t)s6 * 16 + c];
        uint4 v7 = H4[(size_t)s7 * 16 + c];
        ADD8(v0); ADD8(v1); ADD8(v2); ADD8(v3);
        ADD8(v4); ADD8(v5); ADD8(v6); ADD8(v7);
    }
    if (i + 16 <= e) {
        int i0 = i + g4;
        int s0 = csr_src[i0];
        int s1 = csr_src[i0 + 4];
        int s2 = csr_src[i0 + 8];
        int s3 = csr_src[i0 + 12];
        uint4 v0 = H4[(size_t)s0 * 16 + c];
        uint4 v1 = H4[(size_t)s1 * 16 + c];
        uint4 v2 = H4[(size_t)s2 * 16 + c];
        uint4 v3 = H4[(size_t)s3 * 16 + c];
        ADD8(v0); ADD8(v1); ADD8(v2); ADD8(v3);
        i += 16;
    }
    for (; i < e; i += 4) {
        int idx = i + g4;
        bool valid = idx < e;
        int src = csr_src[valid ? idx : (e - 1)];
        uint4 v = H4[(size_t)src * 16 + c];
        if (valid) ADD8(v);
    }
#undef ADD8

#pragma unroll
    for (int j = 0; j < 8; ++j) {
        acc[j] += __shfl_xor(acc[j], 16, 64);
        acc[j] += __shfl_xor(acc[j], 32, 64);
    }
    if (g4 == 0) {
        uint4 o;
        o.x = (unsigned int)f2b_rne(acc[0]) | ((unsigned int)f2b_rne(acc[1]) << 16);
        o.y = (unsigned int)f2b_rne(acc[2]) | ((unsigned int)f2b_rne(acc[3]) << 16);
        o.z = (unsigned int)f2b_rne(acc[4]) | ((unsigned int)f2b_rne(acc[5]) << 16);
        o.w = (unsigned int)f2b_rne(acc[6]) | ((unsigned int)f2b_rne(acc[7]) << 16);
        A4[(size_t)dst * 16 + c] = o;
    }
}

// ------- MFMA GEMM 1: Yb = bf16(A @ W1 + b1), fused BN column stats ---------
__global__ __launch_bounds__(256) void k_mm1(const unsigned short* __restrict__ A,
                                             const unsigned short* __restrict__ Wt,
                                             const float* __restrict__ bias,
                                             unsigned short* __restrict__ Yb,
                                             float* __restrict__ partials) {
    __shared__ float sWS[4 * 128];
    __shared__ float s2WS[4 * 128];
    int wave = threadIdx.x >> 6, lane = threadIdx.x & 63;
    int quad = lane >> 4, l16 = lane & 15;
    int mload = blockIdx.x * 64 + wave * 16 + l16;      // < N_PAD

    short8 a[4];
    const unsigned short* arow = A + (size_t)mload * 128 + quad * 8;
#pragma unroll
    for (int kc = 0; kc < 4; ++kc) a[kc] = *(const short8*)(arow + kc * 32);

    floatx4 acc[8];
#pragma unroll
    for (int nt = 0; nt < 8; ++nt) {
        floatx4 z = {0.f, 0.f, 0.f, 0.f};
        acc[nt] = z;
        const unsigned short* wrow = Wt + (size_t)(nt * 16 + l16) * 128 + quad * 8;
#pragma unroll
        for (int kc = 0; kc < 4; ++kc) {
            short8 b = *(const short8*)(wrow + kc * 32);
            acc[nt] = __builtin_amdgcn_mfma_f32_16x16x32_bf16(a[kc], b, acc[nt], 0, 0, 0);
        }
    }

    int mrow0 = blockIdx.x * 64 + wave * 16 + quad * 4;
    float s_nt[8], s2_nt[8];
#pragma unroll
    for (int nt = 0; nt < 8; ++nt) {
        int n = nt * 16 + l16;
        float bn = bias[n];
        float s = 0.f, s2 = 0.f;
#pragma unroll
        for (int r = 0; r < 4; ++r) {
            int mm = mrow0 + r;
            if (mm < N_NODES) {
                float val = acc[nt][r] + bn;
                Yb[(size_t)mm * 128 + n] = f2b_rne(val);
                s += val;
                s2 = fmaf(val, val, s2);
            }
        }
        s_nt[nt] = s; s2_nt[nt] = s2;
    }
#pragma unroll
    for (int nt = 0; nt < 8; ++nt) {
        s_nt[nt] += __shfl_xor(s_nt[nt], 16, 64);
        s_nt[nt] += __shfl_xor(s_nt[nt], 32, 64);
        s2_nt[nt] += __shfl_xor(s2_nt[nt], 16, 64);
        s2_nt[nt] += __shfl_xor(s2_nt[nt], 32, 64);
    }
    if (quad == 0) {
#pragma unroll
        for (int nt = 0; nt < 8; ++nt) {
            sWS[wave * 128 + nt * 16 + l16] = s_nt[nt];
            s2WS[wave * 128 + nt * 16 + l16] = s2_nt[nt];
        }
    }
    __syncthreads();
    int tid = threadIdx.x;
    if (tid < 128) {
        float v = sWS[tid] + sWS[128 + tid] + sWS[256 + tid] + sWS[384 + tid];
        partials[(size_t)blockIdx.x * 256 + tid] = v;
    } else {
        int cc = tid - 128;
        float v = s2WS[cc] + s2WS[128 + cc] + s2WS[256 + cc] + s2WS[384 + cc];
        partials[(size_t)blockIdx.x * 256 + 128 + cc] = v;
    }
}

// ---- hierarchical partial reduce: 1563 rows -> RED_BLOCKS rows (coalesced) --
__global__ __launch_bounds__(256) void k_redp(const float* __restrict__ partials,
                                              float* __restrict__ pred) {
    int b = blockIdx.x;        // 0..RED_BLOCKS-1
    int tid = threadIdx.x;
    float s = 0.f;
    for (int r = b; r < MM_BLOCKS; r += RED_BLOCKS) s += partials[(size_t)r * 256 + tid];
    pred[(size_t)b * 256 + tid] = s;
}

__global__ __launch_bounds__(256) void k_finalize(const float* __restrict__ pred,
                                                  float* __restrict__ stats,
                                                  const float* __restrict__ g,
                                                  const float* __restrict__ be) {
    __shared__ float red[256];
    int tid = threadIdx.x;
    float s = 0.f;
#pragma unroll 8
    for (int b = 0; b < RED_BLOCKS; ++b) s += pred[(size_t)b * 256 + tid];
    red[tid] = s;
    __syncthreads();
    if (tid < 128) {
        float sum = red[tid], sumsq = red[128 + tid];
        const float invN = 1.f / (float)N_NODES;
        float m = sum * invN;
        float v = sumsq * invN - m * m;
        float rstd = rsqrtf(v + BN_EPS);
        float sca = g[tid] * rstd;
        stats[tid] = sca;
        stats[128 + tid] = be[tid] - m * sca;
    }
}

// ---- MFMA GEMM 2: H = relu( relu(Yb*sc+sh) @ W2 + b2 ), bf16 in/out --------
__global__ __launch_bounds__(256) void k_mm2(const unsigned short* __restrict__ Yb,
                                             const unsigned short* __restrict__ Wt,
                                             const float* __restrict__ bias,
                                             const float* __restrict__ stats,
                                             unsigned short* __restrict__ Hb) {
    int wave = threadIdx.x >> 6, lane = threadIdx.x & 63;
    int quad = lane >> 4, l16 = lane & 15;
    int mload = blockIdx.x * 64 + wave * 16 + l16;

    const unsigned short* yrow = Yb + (size_t)mload * 128;
    short8 a[4];
#pragma unroll
    for (int kc = 0; kc < 4; ++kc) {
        int k0 = kc * 32 + quad * 8;
        union { short8 s8; unsigned short u[8]; } q, p;
        q.s8 = *(const short8*)(yrow + k0);
#pragma unroll
        for (int j = 0; j < 8; ++j) {
            float sc = stats[k0 + j];
            float sh = stats[128 + k0 + j];
            float t = fmaxf(fmaf(bits2f(q.u[j]), sc, sh), 0.f);
            p.u[j] = f2b_rne(t);
        }
        a[kc] = p.s8;
    }

    floatx4 acc[8];
#pragma unroll
    for (int nt = 0; nt < 8; ++nt) {
        floatx4 z = {0.f, 0.f, 0.f, 0.f};
        acc[nt] = z;
        const unsigned short* wrow = Wt + (size_t)(nt * 16 + l16) * 128 + quad * 8;
#pragma unroll
        for (int kc = 0; kc < 4; ++kc) {
            short8 b = *(const short8*)(wrow + kc * 32);
            acc[nt] = __builtin_amdgcn_mfma_f32_16x16x32_bf16(a[kc], b, acc[nt], 0, 0, 0);
        }
    }

    int mrow0 = blockIdx.x * 64 + wave * 16 + quad * 4;
#pragma unroll
    for (int nt = 0; nt < 8; ++nt) {
        int n = nt * 16 + l16;
        float bn = bias[n];
#pragma unroll
        for (int r = 0; r < 4; ++r) {
            int mm = mrow0 + r;
            if (mm < N_NODES) {
                float h = fmaxf(acc[nt][r] + bn, 0.f);
                Hb[(size_t)mm * 128 + n] = f2b_rne(h);
            }
        }
    }
}

// ---------------- global add pool (bf16 in, fp32 out), row-unrolled ---------

__global__ __launch_bounds__(128) void k_pool(const unsigned short* __restrict__ Hb,
                                              const int* __restrict__ startv,
                                              const int* __restrict__ endv,
                                              float* __restrict__ gr, int loff) {
    int g = blockIdx.x;
    int c = threadIdx.x;
    int s = startv[g], e = endv[g];
    float acc = 0.f;
    int r = s;
    for (; r + 4 <= e; r += 4) {
        unsigned short a0 = Hb[(size_t)r * 128 + c];
        unsigned short a1 = Hb[(size_t)(r + 1) * 128 + c];
        unsigned short a2 = Hb[(size_t)(r + 2) * 128 + c];
        unsigned short a3 = Hb[(size_t)(r + 3) * 128 + c];
        acc += bits2f(a0) + bits2f(a1) + bits2f(a2) + bits2f(a3);
    }
    for (; r < e; ++r) acc += bits2f(Hb[(size_t)r * 128 + c]);
    gr[(size_t)g * (4 * DIM) + loff + c] = acc;
}

// ---------------- classifier (fp32 weights, fp32 out) ----------------

__global__ __launch_bounds__(128) void k_cls1(const float* __restrict__ gr,
                                              const float* __restrict__ w,
                                              const float* __restrict__ b,
                                              float* __restrict__ out) {
    __shared__ float row[512];
    int g = blockIdx.x, tid = threadIdx.x;
    for (int i = tid; i < 512; i += 128) row[i] = gr[(size_t)g * 512 + i];
    __syncthreads();
    float acc = b[tid];
    for (int k = 0; k < 512; ++k) acc = fmaf(row[k], w[k * 128 + tid], acc);
    out[(size_t)g * 128 + tid] = fmaxf(acc, 0.f);
}

__global__ __launch_bounds__(64) void k_cls2(const float* __restrict__ gr1,
                                             const float* __restrict__ w,
                                             const float* __restrict__ b,
                                             float* __restrict__ out) {
    __shared__ float row[128];
    int g = blockIdx.x, tid = threadIdx.x;
    row[tid] = gr1[(size_t)g * 128 + tid];
    row[tid + 64] = gr1[(size_t)g * 128 + tid + 64];
    __syncthreads();
    float acc = b[tid];
    for (int k = 0; k < 128; ++k) acc = fmaf(row[k], w[k * 64 + tid], acc);
    out[(size_t)g * 64 + tid] = fmaxf(acc, 0.f);
}

__global__ __launch_bounds__(256) void k_cls3(const float* __restrict__ gr2,
                                              const float* __restrict__ w,
                                              const float* __restrict__ b,
                                              float* __restrict__ out) {
    int idx = blockIdx.x * 256 + threadIdx.x;
    if (idx < N_GRAPHS * 2) {
        int g = idx >> 1, j = idx & 1;
        float acc = b[j];
        const float* r = gr2 + (size_t)g * 64;
        for (int k = 0; k < 64; ++k) acc = fmaf(r[k], w[k * 2 + j], acc);
        out[idx] = acc;
    }
}

// ---------------- launch ----------------

extern "C" void kernel_launch(void* const* d_in, const int* in_sizes, int n_in,
                              void* d_out, int out_size, void* d_ws, size_t ws_size,
                              hipStream_t stream) {
    const float* x = (const float*)d_in[0];
    const int* ei = (const int*)d_in[1];
    const int* batch = (const int*)d_in[2];
    const float* b1 = (const float*)d_in[4];
    const float* g1 = (const float*)d_in[5];
    const float* be1 = (const float*)d_in[6];
    const float* b2 = (const float*)d_in[8];
    const float* lb1 = (const float*)d_in[10];
    const float* lg1 = (const float*)d_in[11];
    const float* lbe1 = (const float*)d_in[12];
    const float* lb2 = (const float*)d_in[14];
    const float* cw1 = (const float*)d_in[15];
    const float* cb1 = (const float*)d_in[16];
    const float* cw2 = (const float*)d_in[17];
    const float* cb2 = (const float*)d_in[18];
    const float* cw3 = (const float*)d_in[19];
    const float* cb3 = (const float*)d_in[20];

    // workspace layout (float units; every segment 16B-aligned)
    float* ws = (float*)d_ws;
    unsigned short* Yb = (unsigned short*)ws;                     // N_PAD*128 bf16
    float* gr = ws + (size_t)N_PAD * 64;                          // 1024*512
    float* gr1 = gr + (size_t)N_GRAPHS * 512;                     // 1024*128
    float* gr2 = gr1 + (size_t)N_GRAPHS * 128;                    // 1024*64
    float* stats = gr2 + (size_t)N_GRAPHS * 64;                   // 256
    float* partials = stats + 256;                                // 1563*256
    float* pred = partials + (size_t)MM_BLOCKS * 256;             // 64*256
    float* p_end = pred + (size_t)RED_BLOCKS * 256;
    int* startv = (int*)p_end;
    int* endv = startv + N_GRAPHS;
    unsigned short* Wt = (unsigned short*)(endv + N_GRAPHS);      // 8*16384 bf16
    unsigned short* A = Wt + (size_t)8 * 16384;                   // N_PAD*128 bf16
    unsigned short* Hb0 = A + (size_t)N_PAD * 128;                // bf16(x)
    unsigned short* Hb1 = Hb0 + (size_t)N_NODES * 128;            // layer H
    int* deg = (int*)(Hb1 + (size_t)N_NODES * 128);               // N_NODES
    int* rank = deg + N_NODES;                                    // N_EDGES
    int* offarr = rank + N_EDGES;                                 // N_NODES+1
    int* csr_src = offarr + (N_NODES + 4);                        // N_EDGES (padded align)
    int* bsum = csr_src + N_EDGES;                                // 256
    int* bbase = bsum + 256;                                      // 256

    k_cvt0<<<12500, 256, 0, stream>>>((const float4*)x, (ushort4*)Hb0);
    k_binit<<<4, 256, 0, stream>>>(startv, endv);
    k_bounds<<<(N_NODES + 255) / 256, 256, 0, stream>>>(batch, startv, endv);
    k_izero<<<(N_NODES + 255) / 256, 256, 0, stream>>>(deg, N_NODES);
    k_deg<<<N_EDGES / 256, 256, 0, stream>>>(ei, deg, rank);
    k_scanA<<<256, 256, 0, stream>>>(deg, bsum);
    k_scanB<<<1, 256, 0, stream>>>(bsum, bbase, &offarr[N_NODES]);
    k_scanC<<<256, 256, 0, stream>>>(deg, bbase, offarr);
    k_fill<<<N_EDGES / 256, 256, 0, stream>>>(ei, offarr, rank, csr_src);
    k_tw<<<512, 256, 0, stream>>>((const float*)d_in[3], (const float*)d_in[7],
                                  (const float*)d_in[9], (const float*)d_in[13], Wt);

    for (int l = 0; l < 4; ++l) {
        const unsigned short* aggIn = (l == 0) ? Hb0 : Hb1;

        const unsigned short* W1t = Wt + (size_t)((l == 0) ? 0 : (1 + l)) * 16384;
        const unsigned short* W2t = Wt + (size_t)((l == 0) ? 1 : (4 + l)) * 16384;
        const float* B1 = (l == 0) ? b1 : lb1 + (size_t)(l - 1) * 128;
        const float* B2 = (l == 0) ? b2 : lb2 + (size_t)(l - 1) * 128;
        const float* G = (l == 0) ? g1 : lg1 + (size_t)(l - 1) * 128;
        const float* BE = (l == 0) ? be1 : lbe1 + (size_t)(l - 1) * 128;

        k_agg<<<N_NODES / 4, 256, 0, stream>>>((const uint4*)aggIn, offarr, csr_src,
                                               (uint4*)A);
        k_mm1<<<MM_BLOCKS, 256, 0, stream>>>(A, W1t, B1, Yb, partials);
        k_redp<<<RED_BLOCKS, 256, 0, stream>>>(partials, pred);
        k_finalize<<<1, 256, 0, stream>>>(pred, stats, G, BE);
        k_mm2<<<MM_BLOCKS, 256, 0, stream>>>(Yb, W2t, B2, stats, Hb1);
        k_pool<<<N_GRAPHS, 128, 0, stream>>>(Hb1, startv, endv, gr, l * DIM);
    }

    k_cls1<<<N_GRAPHS, 128, 0, stream>>>(gr, cw1, cb1, gr1);
    k_cls2<<<N_GRAPHS, 64, 0, stream>>>(gr1, cw2, cb2, gr2);
    k_cls3<<<8, 256, 0, stream>>>(gr2, cw3, cb3, (float*)d_out);
}

// Round 12
// 1231.312 us; speedup vs baseline: 1.5993x; 1.0202x over previous
//
#include <hip/hip_runtime.h>
#include <hip/hip_bf16.h>

#define N_NODES 100000
#define N_PAD 100032          // 1563 * 64
#define MM_BLOCKS 1563        // N_PAD / 64
#define RED_BLOCKS 64
#define N_EDGES 3200000
#define N_GRAPHS 1024
#define DIM 128
#define BN_EPS 1e-5f
#define SCAN_CHUNK 391        // 256 * 391 = 100096 >= N_NODES

typedef __attribute__((ext_vector_type(8))) short short8;
typedef __attribute__((ext_vector_type(4))) float floatx4;

__device__ __forceinline__ float bits2f(unsigned short u) {
    return __uint_as_float(((unsigned int)u) << 16);
}
__device__ __forceinline__ unsigned short f2b_rne(float f) {
    unsigned int u = __float_as_uint(f);
    unsigned int r = u + 0x7FFFu + ((u >> 16) & 1u);
    return (unsigned short)(r >> 16);
}
__device__ __forceinline__ float lo2f(unsigned int u) { return __uint_as_float(u << 16); }
__device__ __forceinline__ float hi2f(unsigned int u) { return __uint_as_float(u & 0xFFFF0000u); }

// ---------------- x (fp32) -> bf16 Hb0, vectorized ----------------
__global__ __launch_bounds__(256) void k_cvt0(const float4* __restrict__ x4,
                                              ushort4* __restrict__ o4) {
    size_t i = (size_t)blockIdx.x * 256 + threadIdx.x;   // exactly 3,200,000
    float4 v = x4[i];
    ushort4 o;
    o.x = f2b_rne(v.x); o.y = f2b_rne(v.y); o.z = f2b_rne(v.z); o.w = f2b_rne(v.w);
    o4[i] = o;
}

// ---------------- graph boundaries (batch sorted) ----------------

__global__ __launch_bounds__(256) void k_binit(int* __restrict__ startv, int* __restrict__ endv) {
    int i = blockIdx.x * 256 + threadIdx.x;
    if (i < N_GRAPHS) { startv[i] = 0; endv[i] = 0; }
}

__global__ __launch_bounds__(256) void k_bounds(const int* __restrict__ batch,
                                                int* __restrict__ startv, int* __restrict__ endv) {
    int i = blockIdx.x * 256 + threadIdx.x;
    if (i >= N_NODES) return;
    int g = batch[i];
    if (i == 0 || batch[i - 1] != g) startv[g] = i;
    if (i == N_NODES - 1 || batch[i + 1] != g) endv[g] = i + 1;
}

// ---------------- CSR build ----------------

__global__ __launch_bounds__(256) void k_izero(int* __restrict__ p, int n) {
    int i = blockIdx.x * 256 + threadIdx.x;
    if (i < n) p[i] = 0;
}

// 8-way split degree histogram: copy = blockIdx&7 (XCD-correlated) cuts
// same-line atomic contention 8x. rank = position within (copy, dst).
__global__ __launch_bounds__(256) void k_deg(const int* __restrict__ ei,
                                             int* __restrict__ deg8,
                                             int* __restrict__ rank) {
    int e = blockIdx.x * 256 + threadIdx.x;
    int copy = blockIdx.x & 7;
    if (e < N_EDGES) rank[e] = atomicAdd(&deg8[copy * N_NODES + ei[N_EDGES + e]], 1);
}

// per-node prefix over the 8 copies; total degree out
__global__ __launch_bounds__(256) void k_comb(const int* __restrict__ deg8,
                                              int* __restrict__ cb8,
                                              int* __restrict__ deg) {
    int i = blockIdx.x * 256 + threadIdx.x;
    if (i >= N_NODES) return;
    int run = 0;
#pragma unroll
    for (int c = 0; c < 8; ++c) {
        cb8[c * N_NODES + i] = run;
        run += deg8[c * N_NODES + i];
    }
    deg[i] = run;
}

// hierarchical scan: A) per-block sums  B) scan of 256 block sums  C) per-node offsets
__global__ __launch_bounds__(256) void k_scanA(const int* __restrict__ deg, int* __restrict__ bsum) {
    __shared__ int red[256];
    int b = blockIdx.x, t = threadIdx.x;
    int base = b * SCAN_CHUNK;
    int end = base + SCAN_CHUNK; if (end > N_NODES) end = N_NODES;
    int s = 0;
    for (int i = base + t; i < end; i += 256) s += deg[i];
    red[t] = s; __syncthreads();
    for (int st = 128; st > 0; st >>= 1) { if (t < st) red[t] += red[t + st]; __syncthreads(); }
    if (t == 0) bsum[b] = red[0];
}

__global__ __launch_bounds__(256) void k_scanB(const int* __restrict__ bsum,
                                               int* __restrict__ bbase, int* __restrict__ offend) {
    __shared__ int v[256];
    int t = threadIdx.x;
    int mine = bsum[t];
    v[t] = mine; __syncthreads();
    for (int d = 1; d < 256; d <<= 1) {
        int x = (t >= d) ? v[t - d] : 0; __syncthreads();
        v[t] += x; __syncthreads();
    }
    bbase[t] = v[t] - mine;
    if (t == 255) *offend = v[255];
}

__global__ __launch_bounds__(256) void k_scanC(const int* __restrict__ deg,
                                               const int* __restrict__ bbase,
                                               int* __restrict__ off) {
    __shared__ int red[256];
    int b = blockIdx.x, t = threadIdx.x;
    int base = b * SCAN_CHUNK;
    int end = base + SCAN_CHUNK; if (end > N_NODES) end = N_NODES;
    int n0 = base + 2 * t, n1 = n0 + 1;
    int d0 = (n0 < end) ? deg[n0] : 0;
    int d1 = (n1 < end) ? deg[n1] : 0;
    int mine = d0 + d1;
    red[t] = mine; __syncthreads();
    for (int d = 1; d < 256; d <<= 1) {
        int x = (t >= d) ? red[t - d] : 0; __syncthreads();
        red[t] += x; __syncthreads();
    }
    int excl = red[t] - mine + bbase[b];
    if (n0 < end) off[n0] = excl;
    if (n1 < end) off[n1] = excl + d0;
}

// atomic-free fill: position = off[dst] + copy-base + rank
__global__ __launch_bounds__(256) void k_fill(const int* __restrict__ ei,
                                              const int* __restrict__ off,
                                              const int* __restrict__ cb8,
                                              const int* __restrict__ rank,
                                              int* __restrict__ csr_src) {
    int e = blockIdx.x * 256 + threadIdx.x;
    int copy = blockIdx.x & 7;
    if (e < N_EDGES) {
        int dst = ei[N_EDGES + e];
        csr_src[off[dst] + cb8[copy * N_NODES + dst] + rank[e]] = ei[e];
    }
}

// ------- weight transpose + fp32->bf16: Wt[mat][n*128+k] = bf16(W[mat][k*128+n])
__global__ __launch_bounds__(256) void k_tw(const float* __restrict__ w1,
                                            const float* __restrict__ w2,
                                            const float* __restrict__ lw1,
                                            const float* __restrict__ lw2,
                                            unsigned short* __restrict__ Wt) {
    int bid = blockIdx.x;                     // 512 blocks
    int mat = bid >> 6;
    int t = (bid & 63) * 256 + threadIdx.x;   // 0..16383
    int k = t >> 7, n = t & 127;
    const float* src;
    if (mat == 0) src = w1;
    else if (mat == 1) src = w2;
    else if (mat < 5) src = lw1 + (size_t)(mat - 2) * 16384;
    else src = lw2 + (size_t)(mat - 5) * 16384;
    Wt[(size_t)mat * 16384 + n * 128 + k] = f2b_rne(src[t]);
}

// ---------------- aggregation: A[dst] = H[dst] + sum_{src in N(dst)} H[src] --
// one wave per dst; 16 lanes x 16B per row => 4 rows/load-instr; main loop 8
// rows in flight; tail is ONE masked batch of 32 (clamped dup loads are cache
// hits) so low-degree nodes keep full MLP.
__global__ __launch_bounds__(256) void k_agg(const uint4* __restrict__ H4,
                                             const int* __restrict__ off,
                                             const int* __restrict__ csr_src,
                                             uint4* __restrict__ A4) {
    int wave = threadIdx.x >> 6;
    int lane = threadIdx.x & 63;
    int g4 = lane >> 4;        // neighbor sub-slot 0..3
    int c = lane & 15;         // uint4 index within 256B row
    int dst = blockIdx.x * 4 + wave;
    if (dst >= N_NODES) return;
    int s = off[dst], e = off[dst + 1];

    float acc[8];
    {
        uint4 h = H4[(size_t)dst * 16 + c];
        if (g4 == 0) {
            acc[0] = lo2f(h.x); acc[1] = hi2f(h.x);
            acc[2] = lo2f(h.y); acc[3] = hi2f(h.y);
            acc[4] = lo2f(h.z); acc[5] = hi2f(h.z);
            acc[6] = lo2f(h.w); acc[7] = hi2f(h.w);
        } else {
#pragma unroll
            for (int j = 0; j < 8; ++j) acc[j] = 0.f;
        }
    }

#define ADD8(v) do { \
        acc[0] += lo2f((v).x); acc[1] += hi2f((v).x); \
        acc[2] += lo2f((v).y); acc[3] += hi2f((v).y); \
        acc[4] += lo2f((v).z); acc[5] += hi2f((v).z); \
        acc[6] += lo2f((v).w); acc[7] += hi2f((v).w); } while (0)

    int i = s;
    for (; i + 32 <= e; i += 32) {
        int i0 = i + g4;
        int s0 = csr_src[i0];
        int s1 = csr_src[i0 + 4];
        int s2 = csr_src[i0 + 8];
        int s3 = csr_src[i0 + 12];
        int s4 = csr_src[i0 + 16];
        int s5 = csr_src[i0 + 20];
        int s6 = csr_src[i0 + 24];
        int s7 = csr_src[i0 + 28];
        uint4 v0 = H4[(size_t)s0 * 16 + c];
        uint4 v1 = H4[(size_t)s1 * 16 + c];
        uint4 v2 = H4[(size_t)s2 * 16 + c];
        uint4 v3 = H4[(size_t)s3 * 16 + c];
        uint4 v4 = H4[(size_t)s4 * 16 + c];
        uint4 v5 = H4[(size_t)s5 * 16 + c];
        uint4 v6 = H4[(size_t)s6 * 16 + c];
        uint4 v7 = H4[(size_t)s7 * 16 + c];
        ADD8(v0); ADD8(v1); ADD8(v2); ADD8(v3);
        ADD8(v4); ADD8(v5); ADD8(v6); ADD8(v7);
    }
    if (i < e) {               // single masked batch, full 8-deep MLP
        int last = e - 1;
        int i0 = i + g4;
        int x0 = i0,      x1 = i0 + 4,  x2 = i0 + 8,  x3 = i0 + 12;
        int x4i = i0 + 16, x5 = i0 + 20, x6 = i0 + 24, x7 = i0 + 28;
        int s0 = csr_src[x0 < e ? x0 : last];
        int s1 = csr_src[x1 < e ? x1 : last];
        int s2 = csr_src[x2 < e ? x2 : last];
        int s3 = csr_src[x3 < e ? x3 : last];
        int s4 = csr_src[x4i < e ? x4i : last];
        int s5 = csr_src[x5 < e ? x5 : last];
        int s6 = csr_src[x6 < e ? x6 : last];
        int s7 = csr_src[x7 < e ? x7 : last];
        uint4 v0 = H4[(size_t)s0 * 16 + c];
        uint4 v1 = H4[(size_t)s1 * 16 + c];
        uint4 v2 = H4[(size_t)s2 * 16 + c];
        uint4 v3 = H4[(size_t)s3 * 16 + c];
        uint4 v4 = H4[(size_t)s4 * 16 + c];
        uint4 v5 = H4[(size_t)s5 * 16 + c];
        uint4 v6 = H4[(size_t)s6 * 16 + c];
        uint4 v7 = H4[(size_t)s7 * 16 + c];
        if (x0 < e) ADD8(v0);
        if (x1 < e) ADD8(v1);
        if (x2 < e) ADD8(v2);
        if (x3 < e) ADD8(v3);
        if (x4i < e) ADD8(v4);
        if (x5 < e) ADD8(v5);
        if (x6 < e) ADD8(v6);
        if (x7 < e) ADD8(v7);
    }
#undef ADD8

#pragma unroll
    for (int j = 0; j < 8; ++j) {
        acc[j] += __shfl_xor(acc[j], 16, 64);
        acc[j] += __shfl_xor(acc[j], 32, 64);
    }
    if (g4 == 0) {
        uint4 o;
        o.x = (unsigned int)f2b_rne(acc[0]) | ((unsigned int)f2b_rne(acc[1]) << 16);
        o.y = (unsigned int)f2b_rne(acc[2]) | ((unsigned int)f2b_rne(acc[3]) << 16);
        o.z = (unsigned int)f2b_rne(acc[4]) | ((unsigned int)f2b_rne(acc[5]) << 16);
        o.w = (unsigned int)f2b_rne(acc[6]) | ((unsigned int)f2b_rne(acc[7]) << 16);
        A4[(size_t)dst * 16 + c] = o;
    }
}

// ------- MFMA GEMM 1: Yb = bf16(A @ W1 + b1), fused BN column stats ---------
__global__ __launch_bounds__(256) void k_mm1(const unsigned short* __restrict__ A,
                                             const unsigned short* __restrict__ Wt,
                                             const float* __restrict__ bias,
                                             unsigned short* __restrict__ Yb,
                                             float* __restrict__ partials) {
    __shared__ float sWS[4 * 128];
    __shared__ float s2WS[4 * 128];
    int wave = threadIdx.x >> 6, lane = threadIdx.x & 63;
    int quad = lane >> 4, l16 = lane & 15;
    int mload = blockIdx.x * 64 + wave * 16 + l16;      // < N_PAD

    short8 a[4];
    const unsigned short* arow = A + (size_t)mload * 128 + quad * 8;
#pragma unroll
    for (int kc = 0; kc < 4; ++kc) a[kc] = *(const short8*)(arow + kc * 32);

    floatx4 acc[8];
#pragma unroll
    for (int nt = 0; nt < 8; ++nt) {
        floatx4 z = {0.f, 0.f, 0.f, 0.f};
        acc[nt] = z;
        const unsigned short* wrow = Wt + (size_t)(nt * 16 + l16) * 128 + quad * 8;
#pragma unroll
        for (int kc = 0; kc < 4; ++kc) {
            short8 b = *(const short8*)(wrow + kc * 32);
            acc[nt] = __builtin_amdgcn_mfma_f32_16x16x32_bf16(a[kc], b, acc[nt], 0, 0, 0);
        }
    }

    int mrow0 = blockIdx.x * 64 + wave * 16 + quad * 4;
    float s_nt[8], s2_nt[8];
#pragma unroll
    for (int nt = 0; nt < 8; ++nt) {
        int n = nt * 16 + l16;
        float bn = bias[n];
        float s = 0.f, s2 = 0.f;
#pragma unroll
        for (int r = 0; r < 4; ++r) {
            int mm = mrow0 + r;
            if (mm < N_NODES) {
                float val = acc[nt][r] + bn;
                Yb[(size_t)mm * 128 + n] = f2b_rne(val);
                s += val;
                s2 = fmaf(val, val, s2);
            }
        }
        s_nt[nt] = s; s2_nt[nt] = s2;
    }
#pragma unroll
    for (int nt = 0; nt < 8; ++nt) {
        s_nt[nt] += __shfl_xor(s_nt[nt], 16, 64);
        s_nt[nt] += __shfl_xor(s_nt[nt], 32, 64);
        s2_nt[nt] += __shfl_xor(s2_nt[nt], 16, 64);
        s2_nt[nt] += __shfl_xor(s2_nt[nt], 32, 64);
    }
    if (quad == 0) {
#pragma unroll
        for (int nt = 0; nt < 8; ++nt) {
            sWS[wave * 128 + nt * 16 + l16] = s_nt[nt];
            s2WS[wave * 128 + nt * 16 + l16] = s2_nt[nt];
        }
    }
    __syncthreads();
    int tid = threadIdx.x;
    if (tid < 128) {
        float v = sWS[tid] + sWS[128 + tid] + sWS[256 + tid] + sWS[384 + tid];
        partials[(size_t)blockIdx.x * 256 + tid] = v;
    } else {
        int cc = tid - 128;
        float v = s2WS[cc] + s2WS[128 + cc] + s2WS[256 + cc] + s2WS[384 + cc];
        partials[(size_t)blockIdx.x * 256 + 128 + cc] = v;
    }
}

// ---- hierarchical partial reduce: 1563 rows -> RED_BLOCKS rows (coalesced) --
__global__ __launch_bounds__(256) void k_redp(const float* __restrict__ partials,
                                              float* __restrict__ pred) {
    int b = blockIdx.x;        // 0..RED_BLOCKS-1
    int tid = threadIdx.x;
    float s = 0.f;
    for (int r = b; r < MM_BLOCKS; r += RED_BLOCKS) s += partials[(size_t)r * 256 + tid];
    pred[(size_t)b * 256 + tid] = s;
}

__global__ __launch_bounds__(256) void k_finalize(const float* __restrict__ pred,
                                                  float* __restrict__ stats,
                                                  const float* __restrict__ g,
                                                  const float* __restrict__ be) {
    __shared__ float red[256];
    int tid = threadIdx.x;
    float s = 0.f;
#pragma unroll 8
    for (int b = 0; b < RED_BLOCKS; ++b) s += pred[(size_t)b * 256 + tid];
    red[tid] = s;
    __syncthreads();
    if (tid < 128) {
        float sum = red[tid], sumsq = red[128 + tid];
        const float invN = 1.f / (float)N_NODES;
        float m = sum * invN;
        float v = sumsq * invN - m * m;
        float rstd = rsqrtf(v + BN_EPS);
        float sca = g[tid] * rstd;
        stats[tid] = sca;
        stats[128 + tid] = be[tid] - m * sca;
    }
}

// ---- MFMA GEMM 2: H = relu( relu(Yb*sc+sh) @ W2 + b2 ), bf16 in/out --------
__global__ __launch_bounds__(256) void k_mm2(const unsigned short* __restrict__ Yb,
                                             const unsigned short* __restrict__ Wt,
                                             const float* __restrict__ bias,
                                             const float* __restrict__ stats,
                                             unsigned short* __restrict__ Hb) {
    int wave = threadIdx.x >> 6, lane = threadIdx.x & 63;
    int quad = lane >> 4, l16 = lane & 15;
    int mload = blockIdx.x * 64 + wave * 16 + l16;

    const unsigned short* yrow = Yb + (size_t)mload * 128;
    short8 a[4];
#pragma unroll
    for (int kc = 0; kc < 4; ++kc) {
        int k0 = kc * 32 + quad * 8;
        union { short8 s8; unsigned short u[8]; } q, p;
        q.s8 = *(const short8*)(yrow + k0);
#pragma unroll
        for (int j = 0; j < 8; ++j) {
            float sc = stats[k0 + j];
            float sh = stats[128 + k0 + j];
            float t = fmaxf(fmaf(bits2f(q.u[j]), sc, sh), 0.f);
            p.u[j] = f2b_rne(t);
        }
        a[kc] = p.s8;
    }

    floatx4 acc[8];
#pragma unroll
    for (int nt = 0; nt < 8; ++nt) {
        floatx4 z = {0.f, 0.f, 0.f, 0.f};
        acc[nt] = z;
        const unsigned short* wrow = Wt + (size_t)(nt * 16 + l16) * 128 + quad * 8;
#pragma unroll
        for (int kc = 0; kc < 4; ++kc) {
            short8 b = *(const short8*)(wrow + kc * 32);
            acc[nt] = __builtin_amdgcn_mfma_f32_16x16x32_bf16(a[kc], b, acc[nt], 0, 0, 0);
        }
    }

    int mrow0 = blockIdx.x * 64 + wave * 16 + quad * 4;
#pragma unroll
    for (int nt = 0; nt < 8; ++nt) {
        int n = nt * 16 + l16;
        float bn = bias[n];
#pragma unroll
        for (int r = 0; r < 4; ++r) {
            int mm = mrow0 + r;
            if (mm < N_NODES) {
                float h = fmaxf(acc[nt][r] + bn, 0.f);
                Hb[(size_t)mm * 128 + n] = f2b_rne(h);
            }
        }
    }
}

// ---------------- global add pool (bf16 in, fp32 out), row-unrolled ---------

__global__ __launch_bounds__(128) void k_pool(const unsigned short* __restrict__ Hb,
                                              const int* __restrict__ startv,
                                              const int* __restrict__ endv,
                                              float* __restrict__ gr, int loff) {
    int g = blockIdx.x;
    int c = threadIdx.x;
    int s = startv[g], e = endv[g];
    float acc = 0.f;
    int r = s;
    for (; r + 4 <= e; r += 4) {
        unsigned short a0 = Hb[(size_t)r * 128 + c];
        unsigned short a1 = Hb[(size_t)(r + 1) * 128 + c];
        unsigned short a2 = Hb[(size_t)(r + 2) * 128 + c];
        unsigned short a3 = Hb[(size_t)(r + 3) * 128 + c];
        acc += bits2f(a0) + bits2f(a1) + bits2f(a2) + bits2f(a3);
    }
    for (; r < e; ++r) acc += bits2f(Hb[(size_t)r * 128 + c]);
    gr[(size_t)g * (4 * DIM) + loff + c] = acc;
}

// ---------------- classifier (fp32 weights, fp32 out) ----------------

__global__ __launch_bounds__(128) void k_cls1(const float* __restrict__ gr,
                                              const float* __restrict__ w,
                                              const float* __restrict__ b,
                                              float* __restrict__ out) {
    __shared__ float row[512];
    int g = blockIdx.x, tid = threadIdx.x;
    for (int i = tid; i < 512; i += 128) row[i] = gr[(size_t)g * 512 + i];
    __syncthreads();
    float acc = b[tid];
    for (int k = 0; k < 512; ++k) acc = fmaf(row[k], w[k * 128 + tid], acc);
    out[(size_t)g * 128 + tid] = fmaxf(acc, 0.f);
}

__global__ __launch_bounds__(64) void k_cls2(const float* __restrict__ gr1,
                                             const float* __restrict__ w,
                                             const float* __restrict__ b,
                                             float* __restrict__ out) {
    __shared__ float row[128];
    int g = blockIdx.x, tid = threadIdx.x;
    row[tid] = gr1[(size_t)g * 128 + tid];
    row[tid + 64] = gr1[(size_t)g * 128 + tid + 64];
    __syncthreads();
    float acc = b[tid];
    for (int k = 0; k < 128; ++k) acc = fmaf(row[k], w[k * 64 + tid], acc);
    out[(size_t)g * 64 + tid] = fmaxf(acc, 0.f);
}

__global__ __launch_bounds__(256) void k_cls3(const float* __restrict__ gr2,
                                              const float* __restrict__ w,
                                              const float* __restrict__ b,
                                              float* __restrict__ out) {
    int idx = blockIdx.x * 256 + threadIdx.x;
    if (idx < N_GRAPHS * 2) {
        int g = idx >> 1, j = idx & 1;
        float acc = b[j];
        const float* r = gr2 + (size_t)g * 64;
        for (int k = 0; k < 64; ++k) acc = fmaf(r[k], w[k * 2 + j], acc);
        out[idx] = acc;
    }
}

// ---------------- launch ----------------

extern "C" void kernel_launch(void* const* d_in, const int* in_sizes, int n_in,
                              void* d_out, int out_size, void* d_ws, size_t ws_size,
                              hipStream_t stream) {
    const float* x = (const float*)d_in[0];
    const int* ei = (const int*)d_in[1];
    const int* batch = (const int*)d_in[2];
    const float* b1 = (const float*)d_in[4];
    const float* g1 = (const float*)d_in[5];
    const float* be1 = (const float*)d_in[6];
    const float* b2 = (const float*)d_in[8];
    const float* lb1 = (const float*)d_in[10];
    const float* lg1 = (const float*)d_in[11];
    const float* lbe1 = (const float*)d_in[12];
    const float* lb2 = (const float*)d_in[14];
    const float* cw1 = (const float*)d_in[15];
    const float* cb1 = (const float*)d_in[16];
    const float* cw2 = (const float*)d_in[17];
    const float* cb2 = (const float*)d_in[18];
    const float* cw3 = (const float*)d_in[19];
    const float* cb3 = (const float*)d_in[20];

    // workspace layout (float units; every segment 16B-aligned)
    float* ws = (float*)d_ws;
    unsigned short* Yb = (unsigned short*)ws;                     // N_PAD*128 bf16
    float* gr = ws + (size_t)N_PAD * 64;                          // 1024*512
    float* gr1 = gr + (size_t)N_GRAPHS * 512;                     // 1024*128
    float* gr2 = gr1 + (size_t)N_GRAPHS * 128;                    // 1024*64
    float* stats = gr2 + (size_t)N_GRAPHS * 64;                   // 256
    float* partials = stats + 256;                                // 1563*256
    float* pred = partials + (size_t)MM_BLOCKS * 256;             // 64*256
    float* p_end = pred + (size_t)RED_BLOCKS * 256;
    int* startv = (int*)p_end;
    int* endv = startv + N_GRAPHS;
    unsigned short* Wt = (unsigned short*)(endv + N_GRAPHS);      // 8*16384 bf16
    unsigned short* A = Wt + (size_t)8 * 16384;                   // N_PAD*128 bf16
    unsigned short* Hb0 = A + (size_t)N_PAD * 128;                // bf16(x)
    unsigned short* Hb1 = Hb0 + (size_t)N_NODES * 128;            // layer H
    int* deg8 = (int*)(Hb1 + (size_t)N_NODES * 128);              // 8*N_NODES
    int* cb8 = deg8 + 8 * N_NODES;                                // 8*N_NODES
    int* deg = cb8 + 8 * N_NODES;                                 // N_NODES
    int* rank = deg + N_NODES;                                    // N_EDGES
    int* offarr = rank + N_EDGES;                                 // N_NODES+1
    int* csr_src = offarr + (N_NODES + 4);                        // N_EDGES
    int* bsum = csr_src + N_EDGES;                                // 256
    int* bbase = bsum + 256;                                      // 256

    k_cvt0<<<12500, 256, 0, stream>>>((const float4*)x, (ushort4*)Hb0);
    k_binit<<<4, 256, 0, stream>>>(startv, endv);
    k_bounds<<<(N_NODES + 255) / 256, 256, 0, stream>>>(batch, startv, endv);
    k_izero<<<(8 * N_NODES + 255) / 256, 256, 0, stream>>>(deg8, 8 * N_NODES);
    k_deg<<<N_EDGES / 256, 256, 0, stream>>>(ei, deg8, rank);
    k_comb<<<(N_NODES + 255) / 256, 256, 0, stream>>>(deg8, cb8, deg);
    k_scanA<<<256, 256, 0, stream>>>(deg, bsum);
    k_scanB<<<1, 256, 0, stream>>>(bsum, bbase, &offarr[N_NODES]);
    k_scanC<<<256, 256, 0, stream>>>(deg, bbase, offarr);
    k_fill<<<N_EDGES / 256, 256, 0, stream>>>(ei, offarr, cb8, rank, csr_src);
    k_tw<<<512, 256, 0, stream>>>((const float*)d_in[3], (const float*)d_in[7],
                                  (const float*)d_in[9], (const float*)d_in[13], Wt);

    for (int l = 0; l < 4; ++l) {
        const unsigned short* aggIn = (l == 0) ? Hb0 : Hb1;

        const unsigned short* W1t = Wt + (size_t)((l == 0) ? 0 : (1 + l)) * 16384;
        const unsigned short* W2t = Wt + (size_t)((l == 0) ? 1 : (4 + l)) * 16384;
        const float* B1 = (l == 0) ? b1 : lb1 + (size_t)(l - 1) * 128;
        const float* B2 = (l == 0) ? b2 : lb2 + (size_t)(l - 1) * 128;
        const float* G = (l == 0) ? g1 : lg1 + (size_t)(l - 1) * 128;
        const float* BE = (l == 0) ? be1 : lbe1 + (size_t)(l - 1) * 128;

        k_agg<<<N_NODES / 4, 256, 0, stream>>>((const uint4*)aggIn, offarr, csr_src,
                                               (uint4*)A);
        k_mm1<<<MM_BLOCKS, 256, 0, stream>>>(A, W1t, B1, Yb, partials);
        k_redp<<<RED_BLOCKS, 256, 0, stream>>>(partials, pred);
        k_finalize<<<1, 256, 0, stream>>>(pred, stats, G, BE);
        k_mm2<<<MM_BLOCKS, 256, 0, stream>>>(Yb, W2t, B2, stats, Hb1);
        k_pool<<<N_GRAPHS, 128, 0, stream>>>(Hb1, startv, endv, gr, l * DIM);
    }

    k_cls1<<<N_GRAPHS, 128, 0, stream>>>(gr, cw1, cb1, gr1);
    k_cls2<<<N_GRAPHS, 64, 0, stream>>>(gr1, cw2, cb2, gr2);
    k_cls3<<<8, 256, 0, stream>>>(gr2, cw3, cb3, (float*)d_out);
}